// Round 9
// baseline (403.439 us; speedup 1.0000x reference)
//
#include <hip/hip_runtime.h>
#include <hip/hip_bf16.h>

// ---------------------------------------------------------------------------
// GATsmall: 2x GATConv (8 heads) + GCNConv head. N=50000, E=500000 (+N self
// loops). Round 9: HEAD-SPLIT fused agg (blockIdx.y = head): per-head bf16
// slice = 3.2MB fits the 4MB per-XCD L2 -> gathers become L2-resident
// (R2's failure revisited with bf16 slice + slot-parallel layout). Merged
// prep kernels (19 -> 15 dispatches). bf16 MFMA GEMMs; fp32 factored logits.
// ---------------------------------------------------------------------------

typedef __attribute__((ext_vector_type(8))) short bf16x8;
typedef __attribute__((ext_vector_type(4))) float f32x4;

// ---------------- CSR build ----------------

__global__ __launch_bounds__(256) void zero_deg_kernel(int* __restrict__ deg, int n) {
    int i = blockIdx.x * 256 + threadIdx.x;
    if (i < n) deg[i] = 0;
}

__global__ __launch_bounds__(256) void hist_kernel(const int* __restrict__ ei, int E, int Etot,
                                                   int* __restrict__ deg) {
    int e = blockIdx.x * 256 + threadIdx.x;
    if (e >= Etot) return;
    int d = (e < E) ? ei[E + e] : (e - E);  // tail = self loops
    atomicAdd(&deg[d], 1);
}

__global__ __launch_bounds__(256) void scanA_kernel(const int* __restrict__ deg,
                                                    int* __restrict__ off,
                                                    int* __restrict__ bsum, int n) {
    __shared__ int buf[256];
    int t = threadIdx.x;
    int i = blockIdx.x * 256 + t;
    int v = (i < n) ? deg[i] : 0;
    buf[t] = v;
    __syncthreads();
    #pragma unroll
    for (int st = 1; st < 256; st <<= 1) {
        int x = (t >= st) ? buf[t - st] : 0;
        __syncthreads();
        buf[t] += x;
        __syncthreads();
    }
    if (i < n) off[i + 1] = buf[t];
    if (t == 255) bsum[blockIdx.x] = buf[255];
}

__global__ __launch_bounds__(256) void scanB_kernel(int* __restrict__ bsum, int nb) {
    __shared__ int buf[256];
    int t = threadIdx.x;
    int v = (t < nb) ? bsum[t] : 0;
    buf[t] = v;
    __syncthreads();
    #pragma unroll
    for (int st = 1; st < 256; st <<= 1) {
        int x = (t >= st) ? buf[t - st] : 0;
        __syncthreads();
        buf[t] += x;
        __syncthreads();
    }
    if (t < nb) bsum[t] = buf[t] - v;  // exclusive prefix of chunk sums
}

__global__ __launch_bounds__(256) void scanC_kernel(const int* __restrict__ deg,
                                                    int* __restrict__ off,
                                                    const int* __restrict__ bsum,
                                                    int* __restrict__ cur,
                                                    float* __restrict__ dinv, int n) {
    int i = blockIdx.x * 256 + threadIdx.x;
    if (i < n) {
        int o = off[i + 1] + bsum[blockIdx.x];
        off[i + 1] = o;
        cur[i] = o - deg[i];
        dinv[i] = rsqrtf((float)deg[i]);  // deg >= 1 (self loop)
    }
    if (i == 0) off[0] = 0;
}

__global__ __launch_bounds__(256) void scatter_kernel(const int* __restrict__ ei, int E, int Etot,
                                                      int* __restrict__ cur,
                                                      int* __restrict__ ssrc) {
    int e = blockIdx.x * 256 + threadIdx.x;
    if (e >= Etot) return;
    int s, d;
    if (e < E) { s = ei[e]; d = ei[E + e]; }
    else       { s = e - E; d = e - E; }
    int pos = atomicAdd(&cur[d], 1);
    ssrc[pos] = s;
}

// ---------------- helpers ----------------

__device__ __forceinline__ float4 bf4_to_f4(uint2 v) {
    float4 r;
    r.x = __uint_as_float((v.x & 0xFFFFu) << 16);
    r.y = __uint_as_float(v.x & 0xFFFF0000u);
    r.z = __uint_as_float((v.y & 0xFFFFu) << 16);
    r.w = __uint_as_float(v.y & 0xFFFF0000u);
    return r;
}

__device__ __forceinline__ ushort f_to_bf(float f) {
    __hip_bfloat16 hb = __float2bfloat16(f);
    return *reinterpret_cast<ushort*>(&hb);
}

// ---------------- merged prep: cvt(x->xb) + wtrans(W1,W2) + wprep(1,2) -----
// job ranges: [0, n*32)                cvt 4 floats each
//             [+0, +32768)             W1t[nn*128+k] = bf(W1[k*256+nn])
//             [+32768, +65536)         W2t[nn*256+k] = bf(W2[k*128+nn])
//             [+65536, +66560)         w1s/w1d (K=128, D=32)
//             [+66560, +68608)         w2s/w2d (K=256, D=16)

__global__ __launch_bounds__(256) void prep_kernel(const float* __restrict__ x,
                                                   const float* __restrict__ W1,
                                                   const float* __restrict__ W2,
                                                   const float* __restrict__ as1,
                                                   const float* __restrict__ ad1,
                                                   const float* __restrict__ as2,
                                                   const float* __restrict__ ad2,
                                                   ushort* __restrict__ xb,
                                                   ushort* __restrict__ W1t,
                                                   ushort* __restrict__ W2t,
                                                   float* __restrict__ w1s,
                                                   float* __restrict__ w1d,
                                                   float* __restrict__ w2s,
                                                   float* __restrict__ w2d, int n) {
    int gid = blockIdx.x * 256 + threadIdx.x;
    const int NCVT = n * 32;
    if (gid < NCVT) {
        int i = gid * 4;
        float4 v = *reinterpret_cast<const float4*>(x + i);
        ushort4 u = make_ushort4(f_to_bf(v.x), f_to_bf(v.y), f_to_bf(v.z), f_to_bf(v.w));
        *reinterpret_cast<ushort4*>(xb + i) = u;
        return;
    }
    gid -= NCVT;
    if (gid < 32768) {  // W1t [256][128]
        int nn = gid >> 7, k = gid & 127;
        W1t[gid] = f_to_bf(W1[(size_t)k * 256 + nn]);
        return;
    }
    gid -= 32768;
    if (gid < 32768) {  // W2t [128][256]
        int nn = gid >> 8, k = gid & 255;
        W2t[gid] = f_to_bf(W2[(size_t)k * 128 + nn]);
        return;
    }
    gid -= 32768;
    if (gid < 1024) {   // wprep1: K=128, D=32
        int k = gid >> 3, h = gid & 7;
        const float* wrow = W1 + (size_t)k * 256 + h * 32;
        const float* as = as1 + h * 32;
        const float* ad = ad1 + h * 32;
        float s1 = 0.f, s2 = 0.f;
        #pragma unroll
        for (int d = 0; d < 32; d += 4) {
            float4 wv = *reinterpret_cast<const float4*>(wrow + d);
            float4 av = *reinterpret_cast<const float4*>(as + d);
            float4 dv = *reinterpret_cast<const float4*>(ad + d);
            s1 += wv.x * av.x + wv.y * av.y + wv.z * av.z + wv.w * av.w;
            s2 += wv.x * dv.x + wv.y * dv.y + wv.z * dv.z + wv.w * dv.w;
        }
        w1s[gid] = s1; w1d[gid] = s2;
        return;
    }
    gid -= 1024;
    if (gid < 2048) {   // wprep2: K=256, D=16
        int k = gid >> 3, h = gid & 7;
        const float* wrow = W2 + (size_t)k * 128 + h * 16;
        const float* as = as2 + h * 16;
        const float* ad = ad2 + h * 16;
        float s1 = 0.f, s2 = 0.f;
        #pragma unroll
        for (int d = 0; d < 16; d += 4) {
            float4 wv = *reinterpret_cast<const float4*>(wrow + d);
            float4 av = *reinterpret_cast<const float4*>(as + d);
            float4 dv = *reinterpret_cast<const float4*>(ad + d);
            s1 += wv.x * av.x + wv.y * av.y + wv.z * av.z + wv.w * av.w;
            s2 += wv.x * dv.x + wv.y * dv.y + wv.z * dv.z + wv.w * dv.w;
        }
        w2s[gid] = s1; w2d[gid] = s2;
    }
}

// a_s[n][8], a_d[n][8] = Xb[n,K](bf16) @ ws/wd[K,8] (fp32 accumulate)
template <int K>
__global__ __launch_bounds__(256) void adots_kernel(const ushort* __restrict__ Xb,
                                                    const float* __restrict__ ws,
                                                    const float* __restrict__ wd,
                                                    float* __restrict__ a_s,
                                                    float* __restrict__ a_d, int n) {
    int gid = blockIdx.x * 256 + threadIdx.x;
    if (gid >= n * 8) return;
    int node = gid >> 3, h = gid & 7;
    const ushort* xp = Xb + (size_t)node * K;
    float s1 = 0.f, s2 = 0.f;
    #pragma unroll 4
    for (int k = 0; k < K; k += 8) {
        uint4 v = *reinterpret_cast<const uint4*>(xp + k);
        float4 x0 = bf4_to_f4(make_uint2(v.x, v.y));
        float4 x1 = bf4_to_f4(make_uint2(v.z, v.w));
        s1 += x0.x * ws[(k + 0) * 8 + h] + x0.y * ws[(k + 1) * 8 + h] +
              x0.z * ws[(k + 2) * 8 + h] + x0.w * ws[(k + 3) * 8 + h] +
              x1.x * ws[(k + 4) * 8 + h] + x1.y * ws[(k + 5) * 8 + h] +
              x1.z * ws[(k + 6) * 8 + h] + x1.w * ws[(k + 7) * 8 + h];
        s2 += x0.x * wd[(k + 0) * 8 + h] + x0.y * wd[(k + 1) * 8 + h] +
              x0.z * wd[(k + 2) * 8 + h] + x0.w * wd[(k + 3) * 8 + h] +
              x1.x * wd[(k + 4) * 8 + h] + x1.y * wd[(k + 5) * 8 + h] +
              x1.z * wd[(k + 6) * 8 + h] + x1.w * wd[(k + 7) * 8 + h];
    }
    a_s[gid] = s1;
    a_d[gid] = s2;
}

// ---------------- bf16 MFMA GEMM: Cb[M,NC] = Ab[M,K] @ Bt[NC,K]^T -----------

template <int K, int NC, int BN>
__global__ __launch_bounds__(256) void mfma_gemm_kernel(const ushort* __restrict__ Ab,
                                                        const ushort* __restrict__ Bt,
                                                        ushort* __restrict__ Cb, int M) {
    constexpr int BM = 128, BK = 32;
    constexpr int FN = BN / 32;
    __shared__ ushort As[BM * BK];
    __shared__ ushort Bs[BN * BK];
    const int tid = threadIdx.x;
    const int lane = tid & 63;
    const int wid = tid >> 6;
    const int bm = blockIdx.y * BM;
    const int bn = blockIdx.x * BN;
    const int wm = (wid >> 1) * 64;
    const int wn = (wid & 1) * (BN / 2);
    const int l15 = lane & 15;
    const int l4 = lane >> 4;
    f32x4 zero4 = {0.f, 0.f, 0.f, 0.f};
    f32x4 acc[4][FN];
    #pragma unroll
    for (int i = 0; i < 4; ++i)
        #pragma unroll
        for (int j = 0; j < FN; ++j) acc[i][j] = zero4;

    for (int k0 = 0; k0 < K; k0 += BK) {
        #pragma unroll
        for (int p = 0; p < 2; ++p) {
            int ci = tid + p * 256;
            int r = ci >> 2, c = ci & 3;
            int row = bm + r;
            uint4 v = make_uint4(0, 0, 0, 0);
            if (row < M) v = *reinterpret_cast<const uint4*>(&Ab[(size_t)row * K + k0 + c * 8]);
            *reinterpret_cast<uint4*>(&As[r * BK + c * 8]) = v;
        }
        #pragma unroll
        for (int p = 0; p < BN / 64; ++p) {
            int ci = tid + p * 256;
            int r = ci >> 2, c = ci & 3;
            uint4 v = *reinterpret_cast<const uint4*>(&Bt[(size_t)(bn + r) * K + k0 + c * 8]);
            *reinterpret_cast<uint4*>(&Bs[r * BK + c * 8]) = v;
        }
        __syncthreads();
        bf16x8 af[4], bfr[FN];
        #pragma unroll
        for (int i = 0; i < 4; ++i)
            af[i] = *reinterpret_cast<const bf16x8*>(&As[(wm + 16 * i + l15) * BK + l4 * 8]);
        #pragma unroll
        for (int j = 0; j < FN; ++j)
            bfr[j] = *reinterpret_cast<const bf16x8*>(&Bs[(wn + 16 * j + l15) * BK + l4 * 8]);
        #pragma unroll
        for (int i = 0; i < 4; ++i)
            #pragma unroll
            for (int j = 0; j < FN; ++j)
                acc[i][j] = __builtin_amdgcn_mfma_f32_16x16x32_bf16(af[i], bfr[j], acc[i][j], 0, 0, 0);
        __syncthreads();
    }
    #pragma unroll
    for (int i = 0; i < 4; ++i) {
        #pragma unroll
        for (int p = 0; p < 4; ++p) {
            int row = bm + wm + 16 * i + l4 * 4 + p;
            if (row < M) {
                #pragma unroll
                for (int j = 0; j < FN; ++j) {
                    Cb[(size_t)row * NC + bn + wn + 16 * j + l15] = f_to_bf(acc[i][j][p]);
                }
            }
        }
    }
}

// ---------------- head-split fused GAT aggregation --------------------------
// blockIdx.y = head h. Per-head gather slice = n * DH * 2B (3.2MB L1 / 1.6MB
// L2) -> per-XCD-L2 resident once ~1 head is live (12.5K+ blocks per head
// serialize the y dim in practice). Lane layout: LPR = DH/8 lanes per row
// slice (uint4 16B each), SLOTS edge-slots in parallel, NPW nodes per wave.
// Per-lane exp (no shfl in loop); cross-slot shfl_xor reduce once per node.

#define LRELU_EXP(e) __expf((e) > 0.f ? (e) : 0.2f * (e))

template <int C, int DH>
__global__ __launch_bounds__(256) void gat_agg_hs_kernel(const ushort* __restrict__ hfeat,
                                                         const float* __restrict__ a_src,
                                                         const float* __restrict__ a_dst,
                                                         const int* __restrict__ off,
                                                         const int* __restrict__ ssrc,
                                                         const float* __restrict__ bias,
                                                         ushort* __restrict__ outb, int n) {
    constexpr int LPR = DH / 8;                 // 4 (L1), 2 (L2)
    constexpr int SLOTS = (DH == 32) ? 16 : 8;  // edge slots in parallel
    constexpr int NPW = 64 / (LPR * SLOTS);     // 1 (L1), 4 (L2)
    const int h = blockIdx.y;
    const int lane = threadIdx.x & 63;
    const int wave = threadIdx.x >> 6;
    const int node = blockIdx.x * (4 * NPW) + wave * NPW + lane / (LPR * SLOTS);
    if (node >= n) return;
    const int lir = lane & (LPR - 1);
    const int slot = (lane / LPR) & (SLOTS - 1);
    const int coff = h * DH + lir * 8;
    const float adst = a_dst[node * 8 + h];
    const int o0 = off[node], o1 = off[node + 1];
    float a0 = 0.f, a1 = 0.f, a2 = 0.f, a3 = 0.f;
    float a4 = 0.f, a5 = 0.f, a6 = 0.f, a7 = 0.f, ssum = 0.f;
    #pragma unroll 2
    for (int i = o0; i < o1; i += SLOTS) {
        int idx = i + slot;
        bool ok = idx < o1;
        int s = ssrc[ok ? idx : (o1 - 1)];
        float e = a_src[s * 8 + h] + adst;
        float ev = ok ? LRELU_EXP(e) : 0.f;
        uint4 rv = *reinterpret_cast<const uint4*>(&hfeat[(size_t)s * C + coff]);
        float4 x0 = bf4_to_f4(make_uint2(rv.x, rv.y));
        float4 x1 = bf4_to_f4(make_uint2(rv.z, rv.w));
        ssum += ev;
        a0 += ev * x0.x; a1 += ev * x0.y; a2 += ev * x0.z; a3 += ev * x0.w;
        a4 += ev * x1.x; a5 += ev * x1.y; a6 += ev * x1.z; a7 += ev * x1.w;
    }
    // reduce across edge slots (lane bits LPR .. LPR*SLOTS/2)
    #pragma unroll
    for (int m = LPR; m < LPR * SLOTS; m <<= 1) {
        ssum += __shfl_xor(ssum, m);
        a0 += __shfl_xor(a0, m); a1 += __shfl_xor(a1, m);
        a2 += __shfl_xor(a2, m); a3 += __shfl_xor(a3, m);
        a4 += __shfl_xor(a4, m); a5 += __shfl_xor(a5, m);
        a6 += __shfl_xor(a6, m); a7 += __shfl_xor(a7, m);
    }
    if (slot == 0) {
        float sinv = 1.f / (ssum + 1e-16f);
        float4 bb0 = *reinterpret_cast<const float4*>(bias + coff);
        float4 bb1 = *reinterpret_cast<const float4*>(bias + coff + 4);
        ushort u[8];
        u[0] = f_to_bf(fmaxf(a0 * sinv + bb0.x, 0.f));
        u[1] = f_to_bf(fmaxf(a1 * sinv + bb0.y, 0.f));
        u[2] = f_to_bf(fmaxf(a2 * sinv + bb0.z, 0.f));
        u[3] = f_to_bf(fmaxf(a3 * sinv + bb0.w, 0.f));
        u[4] = f_to_bf(fmaxf(a4 * sinv + bb1.x, 0.f));
        u[5] = f_to_bf(fmaxf(a5 * sinv + bb1.y, 0.f));
        u[6] = f_to_bf(fmaxf(a6 * sinv + bb1.z, 0.f));
        u[7] = f_to_bf(fmaxf(a7 * sinv + bb1.w, 0.f));
        *reinterpret_cast<uint4*>(&outb[(size_t)node * C + coff]) = *reinterpret_cast<uint4*>(u);
    }
}

// ---------------- GCN head ----------------

// g[node][c] = (out2b[node,:] @ Wg[:,c]) * dinv[node]   (dinv pre-folded)
__global__ __launch_bounds__(256) void gcn_gemm_kernel(const ushort* __restrict__ Ab,
                                                       const float* __restrict__ Wg,
                                                       const float* __restrict__ dinv,
                                                       float* __restrict__ g, int n) {
    __shared__ float W[128 * 8];
    for (int i = threadIdx.x; i < 1024; i += 256) W[i] = Wg[i];
    __syncthreads();
    int gid = blockIdx.x * 256 + threadIdx.x;
    if (gid >= n * 8) return;
    int node = gid >> 3, c = gid & 7;
    const ushort* ap = Ab + (size_t)node * 128;
    float acc = 0.f;
    #pragma unroll
    for (int k = 0; k < 128; k += 8) {
        uint4 v = *reinterpret_cast<const uint4*>(ap + k);
        float4 x0 = bf4_to_f4(make_uint2(v.x, v.y));
        float4 x1 = bf4_to_f4(make_uint2(v.z, v.w));
        acc += x0.x * W[(k + 0) * 8 + c] + x0.y * W[(k + 1) * 8 + c] +
               x0.z * W[(k + 2) * 8 + c] + x0.w * W[(k + 3) * 8 + c] +
               x1.x * W[(k + 4) * 8 + c] + x1.y * W[(k + 5) * 8 + c] +
               x1.z * W[(k + 6) * 8 + c] + x1.w * W[(k + 7) * 8 + c];
    }
    g[gid] = acc * dinv[node];
}

__global__ __launch_bounds__(256) void gcn_agg_kernel(const float* __restrict__ g,
                                                      const float* __restrict__ dinv,
                                                      const int* __restrict__ off,
                                                      const int* __restrict__ ssrc,
                                                      const float* __restrict__ bg,
                                                      float* __restrict__ outp, int n) {
    int gid = blockIdx.x * 256 + threadIdx.x;
    if (gid >= n * 8) return;
    int node = gid >> 3, c = gid & 7;
    int o0 = off[node], o1 = off[node + 1];
    float acc = 0.f;
    for (int i = o0; i < o1; ++i) {
        int s = ssrc[i];
        acc += g[(size_t)s * 8 + c];   // dinv[s] already folded in
    }
    outp[gid] = acc * dinv[node] + bg[c];
}

// ---------------- launch ----------------

extern "C" void kernel_launch(void* const* d_in, const int* in_sizes, int n_in,
                              void* d_out, int out_size, void* d_ws, size_t ws_size,
                              hipStream_t stream) {
    const float* x      = (const float*)d_in[0];
    const int*   ei     = (const int*)d_in[1];
    const float* W1     = (const float*)d_in[2];
    const float* att_s1 = (const float*)d_in[3];
    const float* att_d1 = (const float*)d_in[4];
    const float* b1     = (const float*)d_in[5];
    const float* W2     = (const float*)d_in[6];
    const float* att_s2 = (const float*)d_in[7];
    const float* att_d2 = (const float*)d_in[8];
    const float* b2     = (const float*)d_in[9];
    const float* Wg     = (const float*)d_in[10];
    const float* bg     = (const float*)d_in[11];
    float* out = (float*)d_out;

    const int n    = in_sizes[0] / 128;  // 50000
    const int E    = in_sizes[1] / 2;    // 500000
    const int Etot = E + n;              // 550000

    // workspace carve-up (~70 MB), with region reuse:
    //   regA: h1b bf16 [n,256]  -> out2b bf16 [n,128] (h1b dead after agg1)
    //   regC: xb  bf16 [n,128]  -> h2b  bf16 [n,128]  (xb dead after gemm1)
    float*  wsp   = (float*)d_ws;
    float*  regA  = wsp;                              // [n*128] floats
    float*  regB  = regA + (size_t)n * 128;           // [n*128]: out1b bf16 [n,256]
    float*  regC  = regB + (size_t)n * 128;           // [n*64]
    float*  a_s   = regC + (size_t)n * 64;            // [n*8]
    float*  a_d   = a_s + (size_t)n * 8;              // [n*8]
    float*  g     = a_d + (size_t)n * 8;              // [n*8]
    float*  dinv  = g + (size_t)n * 8;                // [n]
    float*  w1s   = dinv + n;                         // [1024]
    float*  w1d   = w1s + 1024;                       // [1024]
    float*  w2s   = w1d + 1024;                       // [2048]
    float*  w2d   = w2s + 2048;                       // [2048]
    float*  w1t_f = w2d + 2048;                       // W1t bf16 [256][128]
    float*  w2t_f = w1t_f + 16384;                    // W2t bf16 [128][256]
    int*    off   = (int*)(w2t_f + 16384);            // [n+1]
    int*    deg   = off + (n + 1);                    // [n]
    int*    cur   = deg + n;                          // [n]
    int*    ssrc  = cur + n;                          // [Etot]
    int*    bsum  = ssrc + Etot;                      // [<=256]

    ushort* h1b   = (ushort*)regA;
    ushort* out2b = (ushort*)regA;
    ushort* out1b = (ushort*)regB;
    ushort* xb    = (ushort*)regC;
    ushort* h2b   = (ushort*)regC;
    ushort* W1t   = (ushort*)w1t_f;
    ushort* W2t   = (ushort*)w2t_f;

    const dim3 b256(256);
    const int nch = (n + 255) / 256;

    // CSR build
    zero_deg_kernel<<<nch, b256, 0, stream>>>(deg, n);
    hist_kernel<<<(Etot + 255) / 256, b256, 0, stream>>>(ei, E, Etot, deg);
    scanA_kernel<<<nch, b256, 0, stream>>>(deg, off, bsum, n);
    scanB_kernel<<<1, b256, 0, stream>>>(bsum, nch);
    scanC_kernel<<<nch, b256, 0, stream>>>(deg, off, bsum, cur, dinv, n);
    scatter_kernel<<<(Etot + 255) / 256, b256, 0, stream>>>(ei, E, Etot, cur, ssrc);

    // merged prep (cvt + wtrans x2 + wprep x2)
    prep_kernel<<<(n * 32 + 68608 + 255) / 256, b256, 0, stream>>>(
        x, W1, W2, att_s1, att_d1, att_s2, att_d2, xb, W1t, W2t, w1s, w1d, w2s, w2d, n);

    // layer 1: GAT(128 -> 8x32)
    adots_kernel<128><<<(n * 8 + 255) / 256, b256, 0, stream>>>(xb, w1s, w1d, a_s, a_d, n);
    mfma_gemm_kernel<128, 256, 128><<<dim3(2, (n + 127) / 128), b256, 0, stream>>>(xb, W1t, h1b, n);
    gat_agg_hs_kernel<256, 32><<<dim3((n + 3) / 4, 8), b256, 0, stream>>>(h1b, a_s, a_d, off, ssrc, b1, out1b, n);

    // layer 2: GAT(256 -> 8x16)
    adots_kernel<256><<<(n * 8 + 255) / 256, b256, 0, stream>>>(out1b, w2s, w2d, a_s, a_d, n);
    mfma_gemm_kernel<256, 128, 64><<<dim3(2, (n + 127) / 128), b256, 0, stream>>>(out1b, W2t, h2b, n);
    gat_agg_hs_kernel<128, 16><<<dim3((n + 15) / 16, 8), b256, 0, stream>>>(h2b, a_s, a_d, off, ssrc, b2, out2b, n);

    // GCN head
    gcn_gemm_kernel<<<(n * 8 + 255) / 256, b256, 0, stream>>>(out2b, Wg, dinv, g, n);
    gcn_agg_kernel<<<(n * 8 + 255) / 256, b256, 0, stream>>>(g, dinv, off, ssrc, bg, out, n);
}

// Round 11
// 241.131 us; speedup vs baseline: 1.6731x; 1.6731x over previous
//
#include <hip/hip_runtime.h>
#include <hip/hip_bf16.h>

// ---------------------------------------------------------------------------
// GATsmall: 2x GATConv (8 heads) + GCNConv head. N=50000, E=500000 (+N self
// loops). Round 11: R7 structure (proven 263us) with safe kernel merges:
// prep+zero_deg merged, hist+adots1 merged, scanB folded into scanC (per-block
// tree reduce over bsum). 12 dispatches. bf16 MFMA GEMMs; fp32 factored
// attention logits; bf16 tables; dinv folded into gcn_gemm. NO cooperative
// launch (R10 failed: unchecked hipLaunchCooperativeKernel silently no-oped).
// ---------------------------------------------------------------------------

typedef __attribute__((ext_vector_type(8))) short bf16x8;
typedef __attribute__((ext_vector_type(4))) float f32x4;

// ---------------- helpers ----------------

__device__ __forceinline__ float4 bf4_to_f4(uint2 v) {
    float4 r;
    r.x = __uint_as_float((v.x & 0xFFFFu) << 16);
    r.y = __uint_as_float(v.x & 0xFFFF0000u);
    r.z = __uint_as_float((v.y & 0xFFFFu) << 16);
    r.w = __uint_as_float(v.y & 0xFFFF0000u);
    return r;
}

__device__ __forceinline__ ushort f_to_bf(float f) {
    __hip_bfloat16 hb = __float2bfloat16(f);
    return *reinterpret_cast<ushort*>(&hb);
}

// ---------------- K1: prep (zero deg | x->xb | W1t/W2t | factored attn w) ---

__global__ __launch_bounds__(256) void prep_kernel(
    const float* __restrict__ x,
    const float* __restrict__ W1, const float* __restrict__ as1, const float* __restrict__ ad1,
    const float* __restrict__ W2, const float* __restrict__ as2, const float* __restrict__ ad2,
    ushort* __restrict__ xb, ushort* __restrict__ W1t, ushort* __restrict__ W2t,
    float* __restrict__ w1s, float* __restrict__ w1d,
    float* __restrict__ w2s, float* __restrict__ w2d,
    int* __restrict__ deg, int n) {
    const int tid = blockIdx.x * 256 + threadIdx.x;
    const int NT = gridDim.x * 256;
    for (int i = tid; i < n; i += NT) deg[i] = 0;
    for (int j = tid; j < n * 32; j += NT) {
        int i = j * 4;
        float4 v = *reinterpret_cast<const float4*>(x + i);
        ushort4 u = make_ushort4(f_to_bf(v.x), f_to_bf(v.y), f_to_bf(v.z), f_to_bf(v.w));
        *reinterpret_cast<ushort4*>(xb + i) = u;
    }
    for (int j = tid; j < 32768; j += NT) {          // W1t [256][128]
        int nn = j >> 7, k = j & 127;
        W1t[j] = f_to_bf(W1[(size_t)k * 256 + nn]);
    }
    for (int j = tid; j < 32768; j += NT) {          // W2t [128][256]
        int nn = j >> 8, k = j & 255;
        W2t[j] = f_to_bf(W2[(size_t)k * 128 + nn]);
    }
    for (int j = tid; j < 1024; j += NT) {           // wprep1 K=128 D=32
        int k = j >> 3, h = j & 7;
        const float* wrow = W1 + (size_t)k * 256 + h * 32;
        const float* as = as1 + h * 32;
        const float* ad = ad1 + h * 32;
        float s1 = 0.f, s2 = 0.f;
        #pragma unroll
        for (int d = 0; d < 32; d += 4) {
            float4 wv = *reinterpret_cast<const float4*>(wrow + d);
            float4 av = *reinterpret_cast<const float4*>(as + d);
            float4 dv = *reinterpret_cast<const float4*>(ad + d);
            s1 += wv.x * av.x + wv.y * av.y + wv.z * av.z + wv.w * av.w;
            s2 += wv.x * dv.x + wv.y * dv.y + wv.z * dv.z + wv.w * dv.w;
        }
        w1s[j] = s1; w1d[j] = s2;
    }
    for (int j = tid; j < 2048; j += NT) {           // wprep2 K=256 D=16
        int k = j >> 3, h = j & 7;
        const float* wrow = W2 + (size_t)k * 128 + h * 16;
        const float* as = as2 + h * 16;
        const float* ad = ad2 + h * 16;
        float s1 = 0.f, s2 = 0.f;
        #pragma unroll
        for (int d = 0; d < 16; d += 4) {
            float4 wv = *reinterpret_cast<const float4*>(wrow + d);
            float4 av = *reinterpret_cast<const float4*>(as + d);
            float4 dv = *reinterpret_cast<const float4*>(ad + d);
            s1 += wv.x * av.x + wv.y * av.y + wv.z * av.z + wv.w * av.w;
            s2 += wv.x * dv.x + wv.y * dv.y + wv.z * dv.z + wv.w * dv.w;
        }
        w2s[j] = s1; w2d[j] = s2;
    }
}

// ---------------- K2: hist + adots1 (both independent) ----------------------

__global__ __launch_bounds__(256) void hist_adots_kernel(
    const int* __restrict__ ei, int E, int Etot, int* __restrict__ deg,
    const ushort* __restrict__ xb,
    const float* __restrict__ w1s, const float* __restrict__ w1d,
    float* __restrict__ a_s, float* __restrict__ a_d, int n) {
    const int tid = blockIdx.x * 256 + threadIdx.x;
    const int NT = gridDim.x * 256;
    for (int e = tid; e < Etot; e += NT) {
        int d = (e < E) ? ei[E + e] : (e - E);
        atomicAdd(&deg[d], 1);
    }
    for (int j = tid; j < n * 8; j += NT) {
        int node = j >> 3, h = j & 7;
        const ushort* xp = xb + (size_t)node * 128;
        float s1 = 0.f, s2 = 0.f;
        #pragma unroll 4
        for (int k = 0; k < 128; k += 8) {
            uint4 v = *reinterpret_cast<const uint4*>(xp + k);
            float4 x0 = bf4_to_f4(make_uint2(v.x, v.y));
            float4 x1 = bf4_to_f4(make_uint2(v.z, v.w));
            s1 += x0.x * w1s[(k + 0) * 8 + h] + x0.y * w1s[(k + 1) * 8 + h] +
                  x0.z * w1s[(k + 2) * 8 + h] + x0.w * w1s[(k + 3) * 8 + h] +
                  x1.x * w1s[(k + 4) * 8 + h] + x1.y * w1s[(k + 5) * 8 + h] +
                  x1.z * w1s[(k + 6) * 8 + h] + x1.w * w1s[(k + 7) * 8 + h];
            s2 += x0.x * w1d[(k + 0) * 8 + h] + x0.y * w1d[(k + 1) * 8 + h] +
                  x0.z * w1d[(k + 2) * 8 + h] + x0.w * w1d[(k + 3) * 8 + h] +
                  x1.x * w1d[(k + 4) * 8 + h] + x1.y * w1d[(k + 5) * 8 + h] +
                  x1.z * w1d[(k + 6) * 8 + h] + x1.w * w1d[(k + 7) * 8 + h];
        }
        a_s[j] = s1;
        a_d[j] = s2;
    }
}

// ---------------- K3: per-chunk inclusive scan of deg -----------------------

__global__ __launch_bounds__(256) void scanA_kernel(const int* __restrict__ deg,
                                                    int* __restrict__ off,
                                                    int* __restrict__ bsum, int n) {
    __shared__ int buf[256];
    int t = threadIdx.x;
    int i = blockIdx.x * 256 + t;
    int v = (i < n) ? deg[i] : 0;
    buf[t] = v;
    __syncthreads();
    #pragma unroll
    for (int st = 1; st < 256; st <<= 1) {
        int x = (t >= st) ? buf[t - st] : 0;
        __syncthreads();
        buf[t] += x;
        __syncthreads();
    }
    if (i < n) off[i + 1] = buf[t];
    if (t == 255) bsum[blockIdx.x] = buf[255];
}

// ---------------- K4: scanC with in-block bsum prefix (scanB folded) --------
// Each block tree-reduces bsum[0..blockIdx-1] (nch<=256) and applies fixup.

__global__ __launch_bounds__(256) void scanC_kernel(const int* __restrict__ deg,
                                                    int* __restrict__ off,
                                                    const int* __restrict__ bsum,
                                                    int* __restrict__ cur,
                                                    float* __restrict__ dinv, int n) {
    __shared__ int sred[256];
    const int bid = blockIdx.x;
    const int t = threadIdx.x;
    sred[t] = (t < bid) ? bsum[t] : 0;  // bid < nch <= 256
    __syncthreads();
    #pragma unroll
    for (int st = 128; st > 0; st >>= 1) {
        if (t < st) sred[t] += sred[t + st];
        __syncthreads();
    }
    const int pre = sred[0];
    int i = bid * 256 + t;
    if (i < n) {
        int o = off[i + 1] + pre;
        off[i + 1] = o;
        int d = deg[i];
        cur[i] = o - d;
        dinv[i] = rsqrtf((float)d);  // deg >= 1 (self loop)
    }
    if (i == 0) off[0] = 0;
}

// ---------------- K5: scatter ----------------

__global__ __launch_bounds__(256) void scatter_kernel(const int* __restrict__ ei, int E, int Etot,
                                                      int* __restrict__ cur,
                                                      int* __restrict__ ssrc) {
    int e = blockIdx.x * 256 + threadIdx.x;
    if (e >= Etot) return;
    int s, d;
    if (e < E) { s = ei[e]; d = ei[E + e]; }
    else       { s = e - E; d = e - E; }
    int pos = atomicAdd(&cur[d], 1);
    ssrc[pos] = s;
}

// ---------------- adots (layer 2): a = out1b(bf16) @ w2s/w2d ----------------

template <int K>
__global__ __launch_bounds__(256) void adots_kernel(const ushort* __restrict__ Xb,
                                                    const float* __restrict__ ws,
                                                    const float* __restrict__ wd,
                                                    float* __restrict__ a_s,
                                                    float* __restrict__ a_d, int n) {
    int gid = blockIdx.x * 256 + threadIdx.x;
    if (gid >= n * 8) return;
    int node = gid >> 3, h = gid & 7;
    const ushort* xp = Xb + (size_t)node * K;
    float s1 = 0.f, s2 = 0.f;
    #pragma unroll 4
    for (int k = 0; k < K; k += 8) {
        uint4 v = *reinterpret_cast<const uint4*>(xp + k);
        float4 x0 = bf4_to_f4(make_uint2(v.x, v.y));
        float4 x1 = bf4_to_f4(make_uint2(v.z, v.w));
        s1 += x0.x * ws[(k + 0) * 8 + h] + x0.y * ws[(k + 1) * 8 + h] +
              x0.z * ws[(k + 2) * 8 + h] + x0.w * ws[(k + 3) * 8 + h] +
              x1.x * ws[(k + 4) * 8 + h] + x1.y * ws[(k + 5) * 8 + h] +
              x1.z * ws[(k + 6) * 8 + h] + x1.w * ws[(k + 7) * 8 + h];
        s2 += x0.x * wd[(k + 0) * 8 + h] + x0.y * wd[(k + 1) * 8 + h] +
              x0.z * wd[(k + 2) * 8 + h] + x0.w * wd[(k + 3) * 8 + h] +
              x1.x * wd[(k + 4) * 8 + h] + x1.y * wd[(k + 5) * 8 + h] +
              x1.z * wd[(k + 6) * 8 + h] + x1.w * wd[(k + 7) * 8 + h];
    }
    a_s[gid] = s1;
    a_d[gid] = s2;
}

// ---------------- bf16 MFMA GEMM: Cb[M,NC] = Ab[M,K] @ Bt[NC,K]^T -----------

template <int K, int NC, int BN>
__global__ __launch_bounds__(256) void mfma_gemm_kernel(const ushort* __restrict__ Ab,
                                                        const ushort* __restrict__ Bt,
                                                        ushort* __restrict__ Cb, int M) {
    constexpr int BM = 128, BK = 32;
    constexpr int FN = BN / 32;
    __shared__ ushort As[BM * BK];
    __shared__ ushort Bs[BN * BK];
    const int tid = threadIdx.x;
    const int lane = tid & 63;
    const int wid = tid >> 6;
    const int bm = blockIdx.y * BM;
    const int bn = blockIdx.x * BN;
    const int wm = (wid >> 1) * 64;
    const int wn = (wid & 1) * (BN / 2);
    const int l15 = lane & 15;
    const int l4 = lane >> 4;
    f32x4 zero4 = {0.f, 0.f, 0.f, 0.f};
    f32x4 acc[4][FN];
    #pragma unroll
    for (int i = 0; i < 4; ++i)
        #pragma unroll
        for (int j = 0; j < FN; ++j) acc[i][j] = zero4;

    for (int k0 = 0; k0 < K; k0 += BK) {
        #pragma unroll
        for (int p = 0; p < 2; ++p) {
            int ci = tid + p * 256;
            int r = ci >> 2, c = ci & 3;
            int row = bm + r;
            uint4 v = make_uint4(0, 0, 0, 0);
            if (row < M) v = *reinterpret_cast<const uint4*>(&Ab[(size_t)row * K + k0 + c * 8]);
            *reinterpret_cast<uint4*>(&As[r * BK + c * 8]) = v;
        }
        #pragma unroll
        for (int p = 0; p < BN / 64; ++p) {
            int ci = tid + p * 256;
            int r = ci >> 2, c = ci & 3;
            uint4 v = *reinterpret_cast<const uint4*>(&Bt[(size_t)(bn + r) * K + k0 + c * 8]);
            *reinterpret_cast<uint4*>(&Bs[r * BK + c * 8]) = v;
        }
        __syncthreads();
        bf16x8 af[4], bfr[FN];
        #pragma unroll
        for (int i = 0; i < 4; ++i)
            af[i] = *reinterpret_cast<const bf16x8*>(&As[(wm + 16 * i + l15) * BK + l4 * 8]);
        #pragma unroll
        for (int j = 0; j < FN; ++j)
            bfr[j] = *reinterpret_cast<const bf16x8*>(&Bs[(wn + 16 * j + l15) * BK + l4 * 8]);
        #pragma unroll
        for (int i = 0; i < 4; ++i)
            #pragma unroll
            for (int j = 0; j < FN; ++j)
                acc[i][j] = __builtin_amdgcn_mfma_f32_16x16x32_bf16(af[i], bfr[j], acc[i][j], 0, 0, 0);
        __syncthreads();
    }
    #pragma unroll
    for (int i = 0; i < 4; ++i) {
        #pragma unroll
        for (int p = 0; p < 4; ++p) {
            int row = bm + wm + 16 * i + l4 * 4 + p;
            if (row < M) {
                #pragma unroll
                for (int j = 0; j < FN; ++j) {
                    Cb[(size_t)row * NC + bn + wn + 16 * j + l15] = f_to_bf(acc[i][j][p]);
                }
            }
        }
    }
}

// ---------------- fused GAT aggregation (R7 structure, proven 51us) ---------

#define LRELU_EXP(e) __expf((e) > 0.f ? (e) : 0.2f * (e))

template <int C, int DH>
__global__ __launch_bounds__(256) void gat_agg_kernel(const ushort* __restrict__ hfeat,
                                                      const float* __restrict__ a_src,
                                                      const float* __restrict__ a_dst,
                                                      const int* __restrict__ off,
                                                      const int* __restrict__ ssrc,
                                                      const float* __restrict__ bias,
                                                      ushort* __restrict__ outb, int n) {
    constexpr int LPN = C / 4;   // 64 (layer1) or 32 (layer2) lanes per node
    constexpr int GS = DH / 4;   // 8 (layer1) or 4 (layer2) lanes per head
    const int node = blockIdx.x * (256 / LPN) + threadIdx.x / LPN;
    if (node >= n) return;
    const int local = threadIdx.x & (LPN - 1);
    const int c0 = local * 4;
    const int h = c0 / DH;
    const int subl = local & (GS - 1);
    const float adst = a_dst[node * 8 + h];
    const int o0 = off[node], o1 = off[node + 1];
    float ax = 0.f, ay = 0.f, az = 0.f, aw = 0.f, ssum = 0.f;
    int i = o0;
    const int nfull = o0 + ((o1 - o0) / GS) * GS;
    for (; i < nfull; i += GS) {
        int smy = ssrc[i + subl];
        float e = a_src[smy * 8 + h] + adst;
        float evmy = LRELU_EXP(e);
        int sj[GS];
        #pragma unroll
        for (int j = 0; j < GS; ++j) sj[j] = __shfl(smy, j, GS);
        uint2 rv[GS];
        #pragma unroll
        for (int j = 0; j < GS; ++j)
            rv[j] = *reinterpret_cast<const uint2*>(&hfeat[(size_t)sj[j] * C + c0]);
        #pragma unroll
        for (int j = 0; j < GS; ++j) {
            float ev = __shfl(evmy, j, GS);
            float4 hv = bf4_to_f4(rv[j]);
            ssum += ev;
            ax += ev * hv.x; ay += ev * hv.y; az += ev * hv.z; aw += ev * hv.w;
        }
    }
    for (; i < o1; ++i) {
        int s = ssrc[i];
        float e = a_src[s * 8 + h] + adst;
        float v = LRELU_EXP(e);
        uint2 rvv = *reinterpret_cast<const uint2*>(&hfeat[(size_t)s * C + c0]);
        float4 hv = bf4_to_f4(rvv);
        ssum += v;
        ax += v * hv.x; ay += v * hv.y; az += v * hv.z; aw += v * hv.w;
    }
    float sinv = 1.f / (ssum + 1e-16f);
    float4 bb = *reinterpret_cast<const float4*>(bias + c0);
    float ox = fmaxf(ax * sinv + bb.x, 0.f);
    float oy = fmaxf(ay * sinv + bb.y, 0.f);
    float oz = fmaxf(az * sinv + bb.z, 0.f);
    float ow = fmaxf(aw * sinv + bb.w, 0.f);
    ushort4 u = make_ushort4(f_to_bf(ox), f_to_bf(oy), f_to_bf(oz), f_to_bf(ow));
    *reinterpret_cast<ushort4*>(&outb[(size_t)node * C + c0]) = u;
}

// ---------------- GCN head ----------------

__global__ __launch_bounds__(256) void gcn_gemm_kernel(const ushort* __restrict__ Ab,
                                                       const float* __restrict__ Wg,
                                                       const float* __restrict__ dinv,
                                                       float* __restrict__ g, int n) {
    __shared__ float W[128 * 8];
    for (int i = threadIdx.x; i < 1024; i += 256) W[i] = Wg[i];
    __syncthreads();
    int gid = blockIdx.x * 256 + threadIdx.x;
    if (gid >= n * 8) return;
    int node = gid >> 3, c = gid & 7;
    const ushort* ap = Ab + (size_t)node * 128;
    float acc = 0.f;
    #pragma unroll
    for (int k = 0; k < 128; k += 8) {
        uint4 v = *reinterpret_cast<const uint4*>(ap + k);
        float4 x0 = bf4_to_f4(make_uint2(v.x, v.y));
        float4 x1 = bf4_to_f4(make_uint2(v.z, v.w));
        acc += x0.x * W[(k + 0) * 8 + c] + x0.y * W[(k + 1) * 8 + c] +
               x0.z * W[(k + 2) * 8 + c] + x0.w * W[(k + 3) * 8 + c] +
               x1.x * W[(k + 4) * 8 + c] + x1.y * W[(k + 5) * 8 + c] +
               x1.z * W[(k + 6) * 8 + c] + x1.w * W[(k + 7) * 8 + c];
    }
    g[gid] = acc * dinv[node];
}

__global__ __launch_bounds__(256) void gcn_agg_kernel(const float* __restrict__ g,
                                                      const float* __restrict__ dinv,
                                                      const int* __restrict__ off,
                                                      const int* __restrict__ ssrc,
                                                      const float* __restrict__ bg,
                                                      float* __restrict__ outp, int n) {
    int gid = blockIdx.x * 256 + threadIdx.x;
    if (gid >= n * 8) return;
    int node = gid >> 3, c = gid & 7;
    int o0 = off[node], o1 = off[node + 1];
    float acc = 0.f;
    for (int i = o0; i < o1; ++i) {
        int s = ssrc[i];
        acc += g[(size_t)s * 8 + c];   // dinv[s] pre-folded
    }
    outp[gid] = acc * dinv[node] + bg[c];
}

// ---------------- launch ----------------

extern "C" void kernel_launch(void* const* d_in, const int* in_sizes, int n_in,
                              void* d_out, int out_size, void* d_ws, size_t ws_size,
                              hipStream_t stream) {
    const float* x      = (const float*)d_in[0];
    const int*   ei     = (const int*)d_in[1];
    const float* W1     = (const float*)d_in[2];
    const float* att_s1 = (const float*)d_in[3];
    const float* att_d1 = (const float*)d_in[4];
    const float* b1     = (const float*)d_in[5];
    const float* W2     = (const float*)d_in[6];
    const float* att_s2 = (const float*)d_in[7];
    const float* att_d2 = (const float*)d_in[8];
    const float* b2     = (const float*)d_in[9];
    const float* Wg     = (const float*)d_in[10];
    const float* bg     = (const float*)d_in[11];
    float* out = (float*)d_out;

    const int n    = in_sizes[0] / 128;  // 50000
    const int E    = in_sizes[1] / 2;    // 500000
    const int Etot = E + n;              // 550000

    // workspace carve-up (~70 MB), with region reuse:
    //   regA: h1b bf16 [n,256]  -> out2b bf16 [n,128] (h1b dead after agg1)
    //   regC: xb  bf16 [n,128]  -> h2b  bf16 [n,128]  (xb dead after gemm1)
    float*  wsp   = (float*)d_ws;
    float*  regA  = wsp;                              // [n*128] floats
    float*  regB  = regA + (size_t)n * 128;           // [n*128]: out1b bf16 [n,256]
    float*  regC  = regB + (size_t)n * 128;           // [n*64]
    float*  a_s   = regC + (size_t)n * 64;            // [n*8]
    float*  a_d   = a_s + (size_t)n * 8;              // [n*8]
    float*  g     = a_d + (size_t)n * 8;              // [n*8]
    float*  dinv  = g + (size_t)n * 8;                // [n]
    float*  w1s   = dinv + n;                         // [1024]
    float*  w1d   = w1s + 1024;                       // [1024]
    float*  w2s   = w1d + 1024;                       // [2048]
    float*  w2d   = w2s + 2048;                       // [2048]
    float*  w1t_f = w2d + 2048;                       // W1t bf16 [256][128]
    float*  w2t_f = w1t_f + 16384;                    // W2t bf16 [128][256]
    int*    off   = (int*)(w2t_f + 16384);            // [n+1]
    int*    deg   = off + (n + 1);                    // [n]
    int*    cur   = deg + n;                          // [n]
    int*    ssrc  = cur + n;                          // [Etot]
    int*    bsum  = ssrc + Etot;                      // [<=256]

    ushort* h1b   = (ushort*)regA;
    ushort* out2b = (ushort*)regA;
    ushort* out1b = (ushort*)regB;
    ushort* xb    = (ushort*)regC;
    ushort* h2b   = (ushort*)regC;
    ushort* W1t   = (ushort*)w1t_f;
    ushort* W2t   = (ushort*)w2t_f;

    const dim3 b256(256);
    const int nch = (n + 255) / 256;

    // K1: prep (zero deg + cvt + transposes + factored attn weights)
    prep_kernel<<<2048, b256, 0, stream>>>(x, W1, att_s1, att_d1, W2, att_s2, att_d2,
                                           xb, W1t, W2t, w1s, w1d, w2s, w2d, deg, n);
    // K2: hist + adots1
    hist_adots_kernel<<<2048, b256, 0, stream>>>(ei, E, Etot, deg, xb, w1s, w1d, a_s, a_d, n);
    // K3-K5: scan + scatter
    scanA_kernel<<<nch, b256, 0, stream>>>(deg, off, bsum, n);
    scanC_kernel<<<nch, b256, 0, stream>>>(deg, off, bsum, cur, dinv, n);
    scatter_kernel<<<(Etot + 255) / 256, b256, 0, stream>>>(ei, E, Etot, cur, ssrc);

    // layer 1: GAT(128 -> 8x32)
    mfma_gemm_kernel<128, 256, 128><<<dim3(2, (n + 127) / 128), b256, 0, stream>>>(xb, W1t, h1b, n);
    gat_agg_kernel<256, 32><<<(n + 3) / 4, b256, 0, stream>>>(h1b, a_s, a_d, off, ssrc, b1, out1b, n);

    // layer 2: GAT(256 -> 8x16)
    adots_kernel<256><<<(n * 8 + 255) / 256, b256, 0, stream>>>(out1b, w2s, w2d, a_s, a_d, n);
    mfma_gemm_kernel<256, 128, 64><<<dim3(2, (n + 127) / 128), b256, 0, stream>>>(out1b, W2t, h2b, n);
    gat_agg_kernel<128, 16><<<(n + 7) / 8, b256, 0, stream>>>(h2b, a_s, a_d, off, ssrc, b2, out2b, n);

    // GCN head
    gcn_gemm_kernel<<<(n * 8 + 255) / 256, b256, 0, stream>>>(out2b, Wg, dinv, g, n);
    gcn_agg_kernel<<<(n * 8 + 255) / 256, b256, 0, stream>>>(g, dinv, off, ssrc, bg, out, n);
}